// Round 1
// 313.403 us; speedup vs baseline: 1.1905x; 1.1905x over previous
//
#include <hip/hip_runtime.h>
#include <stdint.h>

#define EMB 1024
#define LROW 40   // staging LDS pitch (u16) for the reg-staged (mixed) GEMM

typedef unsigned short u16;
typedef __attribute__((ext_vector_type(8))) unsigned short u16x8;
typedef __attribute__((ext_vector_type(8))) __bf16 bf16x8;
typedef __attribute__((ext_vector_type(4))) float f32x4;

__device__ __forceinline__ u16 f2bf(float f) {
  union { float f; uint32_t u; } x; x.f = f;
  uint32_t u = x.u;
  u += 0x7fff + ((u >> 16) & 1u);   // round-to-nearest-even
  return (u16)(u >> 16);
}

// Load 8 contiguous elements (f32 -> cvt to bf16, or raw bf16) as u16x8 bits.
template<int F32>
__device__ __forceinline__ u16x8 ld8(const void* p, size_t off) {
  if (F32) {
    const float4* f = (const float4*)((const float*)p + off);
    const float4 lo = f[0], hi = f[1];
    u16x8 r;
    r[0] = f2bf(lo.x); r[1] = f2bf(lo.y); r[2] = f2bf(lo.z); r[3] = f2bf(lo.w);
    r[4] = f2bf(hi.x); r[5] = f2bf(hi.y); r[6] = f2bf(hi.z); r[7] = f2bf(hi.w);
    return r;
  }
  return *(const u16x8*)((const u16*)p + off);
}

// Async global->LDS, 16B per lane. LDS dest is wave-uniform base + lane*16.
__device__ __forceinline__ void gl16(const u16* g, u16* l) {
  __builtin_amdgcn_global_load_lds(
      (const __attribute__((address_space(1))) void*)g,
      (__attribute__((address_space(3))) void*)l, 16, 0, 0);
}

// ---------------------------------------------------------------------------
// f32 -> bf16 bulk convert (grid-stride, 8 elems/thread/iter). Two source
// ranges fused into one launch (activation tensor + weight matrix).
// Memory-bound: ~5+ TB/s expected.
// ---------------------------------------------------------------------------
__global__ __launch_bounds__(256) void cvt2_kernel(
    const float* __restrict__ a0, u16* __restrict__ b0, int n0,
    const float* __restrict__ a1, u16* __restrict__ b1, int n1)
{
  int i = blockIdx.x * 256 + threadIdx.x;
  const int stride = gridDim.x * 256;
  const int tot = n0 + n1;
  for (; i < tot; i += stride) {
    const float* src; u16* dst; int j;
    if (i < n0) { src = a0; dst = b0; j = i; }
    else        { src = a1; dst = b1; j = i - n0; }
    const float4* f = (const float4*)(src + (size_t)j * 8);
    const float4 lo = f[0], hi = f[1];
    u16x8 r;
    r[0] = f2bf(lo.x); r[1] = f2bf(lo.y); r[2] = f2bf(lo.z); r[3] = f2bf(lo.w);
    r[4] = f2bf(hi.x); r[5] = f2bf(hi.y); r[6] = f2bf(hi.z); r[7] = f2bf(hi.w);
    *(u16x8*)(dst + (size_t)j * 8) = r;
  }
}

// ---------------------------------------------------------------------------
// All-bf16 GEMM tile (C = X @ W^T + bias), m97 structure:
//   global_load_lds width=16 staging, single LDS buffer, 2 barriers/K-step.
// LDS layout: linear 128x32 bf16 (64B rows), XOR-swizzled 16B slots
// (phys slot = logical slot ^ (row&3)) applied identically on the staging
// SOURCE address and the frag READ -> conflict-optimal ds_read_b128
// (8 lanes per 16B bank group, the wave64 minimum). Rule #21 compliant:
// linear dest + inverse-swz source + same-XOR read.
// ---------------------------------------------------------------------------
template<int CF32>
__device__ __forceinline__ void gemm_lds_core(
    const u16* __restrict__ X, const u16* __restrict__ W,
    const float* __restrict__ Bias, void* __restrict__ C,
    int bm, int bn, int N, int K, u16* Al, u16* Bl)
{
  const int tid  = threadIdx.x;
  const int lane = tid & 63;
  const int w    = tid >> 6;
  const int wm = w >> 1, wn = w & 1;
  const int r16 = lane & 15, quad = lane >> 4;

  // 512 x 16B segments per tile; wave w stages segs [w*64, w*64+64) and
  // [256+w*64, ...). Physical seg s holds logical (row=s>>2, slot=(s&3)^(row&3)).
  const int s0 = w * 64 + lane;
  const int s1 = s0 + 256;
  const int r0 = s0 >> 2, c0 = ((s0 & 3) ^ (r0 & 3)) * 8;
  const int r1 = s1 >> 2, c1 = ((s1 & 3) ^ (r1 & 3)) * 8;

  const u16* srcA0 = X + (size_t)(bm + r0) * K + c0;
  const u16* srcA1 = X + (size_t)(bm + r1) * K + c1;
  const u16* srcB0 = W + (size_t)(bn + r0) * K + c0;
  const u16* srcB1 = W + (size_t)(bn + r1) * K + c1;

  u16* dA0 = Al + (w * 64) * 8;       // wave-uniform LDS bases
  u16* dA1 = dA0 + 256 * 8;
  u16* dB0 = Bl + (w * 64) * 8;
  u16* dB1 = dB0 + 256 * 8;

  // frag read offsets (u16 units): row*32 + (quad ^ (row&3))*8, row&3 == r16&3
  const int swz = (quad ^ (r16 & 3)) * 8;
  int offA[4], offB[4];
#pragma unroll
  for (int t = 0; t < 4; t++) {
    offA[t] = (wm * 64 + t * 16 + r16) * 32 + swz;
    offB[t] = (wn * 64 + t * 16 + r16) * 32 + swz;
  }

  f32x4 acc[4][4];
#pragma unroll
  for (int i = 0; i < 4; i++)
#pragma unroll
    for (int j = 0; j < 4; j++)
      acc[i][j] = f32x4{0.f, 0.f, 0.f, 0.f};

  for (int k0 = 0; k0 < K; k0 += 32) {
    gl16(srcA0 + k0, dA0);
    gl16(srcA1 + k0, dA1);
    gl16(srcB0 + k0, dB0);
    gl16(srcB1 + k0, dB1);
    __syncthreads();              // compiler drains vmcnt(0) before s_barrier

    bf16x8 a[4], b[4];
#pragma unroll
    for (int t = 0; t < 4; t++) a[t] = *(const bf16x8*)&Al[offA[t]];
#pragma unroll
    for (int t = 0; t < 4; t++) b[t] = *(const bf16x8*)&Bl[offB[t]];

#pragma unroll
    for (int tm = 0; tm < 4; tm++)
#pragma unroll
      for (int tn = 0; tn < 4; tn++)
        acc[tm][tn] = __builtin_amdgcn_mfma_f32_16x16x32_bf16(a[tm], b[tn], acc[tm][tn], 0, 0, 0);
    __syncthreads();
  }

  // C/D layout: col = lane&15, row = quad*4 + reg  (verified m89/m91)
#pragma unroll
  for (int tn = 0; tn < 4; tn++) {
    const int col = bn + wn * 64 + tn * 16 + r16;
    const float bias = Bias[col];
#pragma unroll
    for (int tm = 0; tm < 4; tm++) {
      const int row0 = bm + wm * 64 + tm * 16 + quad * 4;
#pragma unroll
      for (int r = 0; r < 4; r++) {
        const float val = acc[tm][tn][r] + bias;
        const size_t idx = (size_t)(row0 + r) * N + col;
        if (CF32) ((float*)C)[idx] = val;
        else      ((u16*)C)[idx]   = f2bf(val);
      }
    }
  }
}

__global__ __launch_bounds__(256, 3) void gemm_bf16_b16out_kernel(
    const u16* __restrict__ X, const u16* __restrict__ W,
    const float* __restrict__ B, u16* __restrict__ C, int N, int K)
{
  __shared__ __attribute__((aligned(16))) u16 Al[128 * 32];
  __shared__ __attribute__((aligned(16))) u16 Bl[128 * 32];
  gemm_lds_core<0>(X, W, B, C, blockIdx.y * 128, blockIdx.x * 128, N, K, Al, Bl);
}

__global__ __launch_bounds__(256, 3) void gemm_bf16_f32out_kernel(
    const u16* __restrict__ X, const u16* __restrict__ W,
    const float* __restrict__ B, float* __restrict__ C, int N, int K)
{
  __shared__ __attribute__((aligned(16))) u16 Al[128 * 32];
  __shared__ __attribute__((aligned(16))) u16 Bl[128 * 32];
  gemm_lds_core<1>(X, W, B, C, blockIdx.y * 128, blockIdx.x * 128, N, K, Al, Bl);
}

// ---------------------------------------------------------------------------
// Mixed GEMM (X bf16 reg-staged, W f32 converted in-loop): used only for the
// K projection, whose bf16 weight has no free scratch home at its phase
// (q, v, Xbuf all live; ws budget held at the proven 2*M*EMB*2 bytes).
// This is the previously-proven gemm_core path.
// ---------------------------------------------------------------------------
template<int XF32, int CF32>
__device__ __forceinline__ void gemm_core(
    const void* __restrict__ X, const float* __restrict__ W,
    const float* __restrict__ Bias, void* __restrict__ C,
    int bm, int bn, int N, int K, u16* Al, u16* Bl)
{
  const int tid  = threadIdx.x;
  const int lane = tid & 63;
  const int w    = tid >> 6;
  const int wm = w >> 1, wn = w & 1;
  const int r16 = lane & 15, quad = lane >> 4;

  const int s0 = tid, s1 = tid + 256;
  const int r0 = s0 >> 2, k0o = (s0 & 3) * 8;
  const int r1 = s1 >> 2, k1o = (s1 & 3) * 8;
  const int l0 = r0 * LROW + k0o;
  const int l1 = r1 * LROW + k1o;

  const size_t xo0 = (size_t)(bm + r0) * K + k0o;
  const size_t xo1 = (size_t)(bm + r1) * K + k1o;
  const size_t wo0 = (size_t)(bn + r0) * K + k0o;
  const size_t wo1 = (size_t)(bn + r1) * K + k1o;

  f32x4 acc[4][4];
#pragma unroll
  for (int i = 0; i < 4; i++)
#pragma unroll
    for (int j = 0; j < 4; j++)
      acc[i][j] = f32x4{0.f, 0.f, 0.f, 0.f};

  u16x8 xa = ld8<XF32>(X, xo0);
  u16x8 xb = ld8<XF32>(X, xo1);
  u16x8 wa = ld8<1>(W, wo0);
  u16x8 wb = ld8<1>(W, wo1);

  for (int k0 = 0; k0 < K; k0 += 32) {
    *(u16x8*)&Al[l0] = xa;
    *(u16x8*)&Al[l1] = xb;
    *(u16x8*)&Bl[l0] = wa;
    *(u16x8*)&Bl[l1] = wb;
    __syncthreads();

    const int kn = (k0 + 32 < K) ? (k0 + 32) : 0;
    xa = ld8<XF32>(X, xo0 + kn);
    xb = ld8<XF32>(X, xo1 + kn);
    wa = ld8<1>(W, wo0 + kn);
    wb = ld8<1>(W, wo1 + kn);

    bf16x8 a[4], b[4];
#pragma unroll
    for (int t = 0; t < 4; t++)
      a[t] = *(const bf16x8*)&Al[(wm * 64 + t * 16 + r16) * LROW + quad * 8];
#pragma unroll
    for (int t = 0; t < 4; t++)
      b[t] = *(const bf16x8*)&Bl[(wn * 64 + t * 16 + r16) * LROW + quad * 8];

#pragma unroll
    for (int tm = 0; tm < 4; tm++)
#pragma unroll
      for (int tn = 0; tn < 4; tn++)
        acc[tm][tn] = __builtin_amdgcn_mfma_f32_16x16x32_bf16(a[tm], b[tn], acc[tm][tn], 0, 0, 0);
    __syncthreads();
  }

#pragma unroll
  for (int tn = 0; tn < 4; tn++) {
    const int col = bn + wn * 64 + tn * 16 + r16;
    const float bias = Bias[col];
#pragma unroll
    for (int tm = 0; tm < 4; tm++) {
      const int row0 = bm + wm * 64 + tm * 16 + quad * 4;
#pragma unroll
      for (int r = 0; r < 4; r++) {
        const float val = acc[tm][tn][r] + bias;
        const size_t idx = (size_t)(row0 + r) * N + col;
        if (CF32) ((float*)C)[idx] = val;
        else      ((u16*)C)[idx]   = f2bf(val);
      }
    }
  }
}

__global__ __launch_bounds__(256, 2) void gemm_mixed_kernel(
    const u16* X, const float* W, const float* B, u16* C, int N, int K)
{
  __shared__ __attribute__((aligned(16))) u16 Al[128 * LROW];
  __shared__ __attribute__((aligned(16))) u16 Bl[128 * LROW];
  gemm_core<0, 0>(X, W, B, C, blockIdx.y * 128, blockIdx.x * 128, N, K, Al, Bl);
}

// ---------------------------------------------------------------------------
// Per-token head-mixing attention (unchanged logic; occupancy raised 2->4
// blocks/CU -- LDS allows 6, VGPR cap 128 is ample for this kernel).
// ---------------------------------------------------------------------------
__global__ __launch_bounds__(256, 4) void attn_heads_kernel(
    const u16* Q, const u16* Km, const u16* V, u16* O)
{
  __shared__ __attribute__((aligned(16))) u16 P[4][16 * LROW];
  __shared__ __attribute__((aligned(16))) u16 VT[4][64 * LROW];

  const int tid = threadIdx.x, lane = tid & 63, w = tid >> 6;
  const int r16 = lane & 15, quad = lane >> 4;
  const size_t base = ((size_t)blockIdx.x * 4 + w) * EMB;

  const bf16x8 aq0 = *(const bf16x8*)&Q[base + r16 * 64 + quad * 8];
  const bf16x8 aq1 = *(const bf16x8*)&Q[base + r16 * 64 + 32 + quad * 8];
  const bf16x8 bk0 = *(const bf16x8*)&Km[base + r16 * 64 + quad * 8];
  const bf16x8 bk1 = *(const bf16x8*)&Km[base + r16 * 64 + 32 + quad * 8];

  const u16x8 v0 = *(const u16x8*)&V[base + lane * 16];
  const u16x8 v1 = *(const u16x8*)&V[base + lane * 16 + 8];
  const u16x8 z8 = {0, 0, 0, 0, 0, 0, 0, 0};
  *(u16x8*)&VT[w][lane * LROW + 16] = z8;
  *(u16x8*)&VT[w][lane * LROW + 24] = z8;
  const int g = lane >> 2, dbase = (lane & 3) * 16;
#pragma unroll
  for (int i = 0; i < 8; i++) {
    VT[w][(dbase + i) * LROW + g]     = v0[i];
    VT[w][(dbase + 8 + i) * LROW + g] = v1[i];
  }

  f32x4 s = f32x4{0.f, 0.f, 0.f, 0.f};
  s = __builtin_amdgcn_mfma_f32_16x16x32_bf16(aq0, bk0, s, 0, 0, 0);
  s = __builtin_amdgcn_mfma_f32_16x16x32_bf16(aq1, bk1, s, 0, 0, 0);

  float p[4];
#pragma unroll
  for (int r = 0; r < 4; r++) {
    float v = s[r] * 0.125f;
    float m = v;
#pragma unroll
    for (int d = 8; d; d >>= 1) m = fmaxf(m, __shfl_xor(m, d, 16));
    float e = __expf(v - m);
    float sum = e;
#pragma unroll
    for (int d = 8; d; d >>= 1) sum += __shfl_xor(sum, d, 16);
    p[r] = e / sum;
  }

#pragma unroll
  for (int r = 0; r < 4; r++) {
    P[w][(quad * 4 + r) * LROW + r16]      = f2bf(p[r]);
    P[w][(quad * 4 + r) * LROW + 16 + r16] = 0;
  }
  __syncthreads();

  const bf16x8 pa = *(const bf16x8*)&P[w][r16 * LROW + quad * 8];

#pragma unroll
  for (int c = 0; c < 4; c++) {
    const bf16x8 bv = *(const bf16x8*)&VT[w][(c * 16 + r16) * LROW + quad * 8];
    f32x4 o = f32x4{0.f, 0.f, 0.f, 0.f};
    o = __builtin_amdgcn_mfma_f32_16x16x32_bf16(pa, bv, o, 0, 0, 0);
#pragma unroll
    for (int r = 0; r < 4; r++)
      O[base + (size_t)(quad * 4 + r) * 64 + c * 16 + r16] = f2bf(o[r]);
  }
}

// ---------------------------------------------------------------------------
// Orchestration. ws footprint: exactly 2*M*EMB*2 bytes (q | k-region), same
// as the proven baseline. d_out: lower half = v (bf16), upper half = Xbuf.
// Wq/Wv bf16 borrow the not-yet-written k-region; Wo bf16 reuses it after
// attention (k dead). Order Q -> V -> K(mixed) -> attn -> out.
// ---------------------------------------------------------------------------
extern "C" void kernel_launch(void* const* d_in, const int* in_sizes, int n_in,
                              void* d_out, int out_size, void* d_ws, size_t ws_size,
                              hipStream_t stream)
{
  const float* values = (const float*)d_in[0];
  const float* keys   = (const float*)d_in[1];
  const float* query  = (const float*)d_in[2];
  const float* Wv = (const float*)d_in[3];
  const float* bv = (const float*)d_in[4];
  const float* Wk = (const float*)d_in[5];
  const float* bk = (const float*)d_in[6];
  const float* Wq = (const float*)d_in[7];
  const float* bq = (const float*)d_in[8];
  const float* Wo = (const float*)d_in[9];
  const float* bo = (const float*)d_in[10];

  const int M = in_sizes[0] / EMB;   // 8192 tokens
  const int N = EMB, K = EMB;

  u16* q    = (u16*)d_ws;                 // M*EMB bf16
  u16* kbuf = q + (size_t)M * EMB;        // M*EMB bf16 (k; earlier: Wq/Wv/Wo bf16 scratch)
  u16* v    = (u16*)d_out;                // lower half of d_out
  u16* xbuf = v + (size_t)M * EMB;        // upper half of d_out
  u16* ao   = q;                          // attention out aliases q
  u16* wqb  = kbuf;                       // 2 MB
  u16* wvb  = kbuf + (size_t)EMB * EMB;   // next 2 MB
  u16* wob  = kbuf;                       // reused after attn (k dead at out-GEMM)

  const int n8X = M * EMB / 8;
  const int n8W = EMB * EMB / 8;

  dim3 blk(256, 1, 1);
  dim3 cg(2048, 1, 1);
  dim3 gg(N / 128, M / 128, 1);

  // Q projection
  hipLaunchKernelGGL(cvt2_kernel, cg, blk, 0, stream, query, xbuf, n8X, Wq, wqb, n8W);
  hipLaunchKernelGGL(gemm_bf16_b16out_kernel, gg, blk, 0, stream, xbuf, wqb, bq, q, N, K);
  // V projection (reads xbuf = d_out upper, writes v = d_out lower)
  hipLaunchKernelGGL(cvt2_kernel, cg, blk, 0, stream, values, xbuf, n8X, Wv, wvb, n8W);
  hipLaunchKernelGGL(gemm_bf16_b16out_kernel, gg, blk, 0, stream, xbuf, wvb, bv, v, N, K);
  // K projection (mixed: W stays f32, converted in-loop; writes over wqb/wvb -- dead)
  hipLaunchKernelGGL(cvt2_kernel, cg, blk, 0, stream, keys, xbuf, n8X,
                     (const float*)nullptr, (u16*)nullptr, 0);
  hipLaunchKernelGGL(gemm_mixed_kernel, gg, blk, 0, stream, xbuf, Wk, bk, kbuf, N, K);
  // attention
  hipLaunchKernelGGL(attn_heads_kernel, dim3(M / 4, 1, 1), blk, 0, stream, q, kbuf, v, ao);
  // output projection (k region dead -> hosts Wo bf16; writes all of d_out f32)
  hipLaunchKernelGGL(cvt2_kernel, cg, blk, 0, stream, Wo, wob, n8W,
                     (const float*)nullptr, (u16*)nullptr, 0);
  hipLaunchKernelGGL(gemm_bf16_f32out_kernel, gg, blk, 0, stream, ao, wob, bo, (float*)d_out, N, K);
}

// Round 2
// 298.192 us; speedup vs baseline: 1.2512x; 1.0510x over previous
//
#include <hip/hip_runtime.h>
#include <stdint.h>

#define EMB 1024
#define LROW 40   // attn-kernel LDS pitch (u16)

typedef unsigned short u16;
typedef __attribute__((ext_vector_type(8))) unsigned short u16x8;
typedef __attribute__((ext_vector_type(8))) __bf16 bf16x8;
typedef __attribute__((ext_vector_type(4))) float f32x4;

__device__ __forceinline__ u16 f2bf(float f) {
  union { float f; uint32_t u; } x; x.f = f;
  uint32_t u = x.u;
  u += 0x7fff + ((u >> 16) & 1u);   // round-to-nearest-even
  return (u16)(u >> 16);
}

// 8x f32 -> bf16x8 via native casts: compiler emits v_cvt_pk_bf16_f32 (RNE),
// ~3x fewer VALU ops than the manual bit-twiddle.
__device__ __forceinline__ bf16x8 cvt8(float4 a, float4 b) {
  bf16x8 r;
  r[0] = (__bf16)a.x; r[1] = (__bf16)a.y; r[2] = (__bf16)a.z; r[3] = (__bf16)a.w;
  r[4] = (__bf16)b.x; r[5] = (__bf16)b.y; r[6] = (__bf16)b.z; r[7] = (__bf16)b.w;
  return r;
}

// Async global->LDS, 16B per lane. LDS dest is wave-uniform base + lane*16.
__device__ __forceinline__ void gl16(const u16* g, u16* l) {
  __builtin_amdgcn_global_load_lds(
      (const __attribute__((address_space(1))) void*)g,
      (__attribute__((address_space(3))) void*)l, 16, 0, 0);
}

// ---------------------------------------------------------------------------
// Weight cvt: y-indexed (src,dst) pairs, each exactly EMB*EMB elements.
// grid = (EMB*EMB/8/256, nPairs). Memory-bound, ~2 us total for 3-4 weights.
// ---------------------------------------------------------------------------
__global__ __launch_bounds__(256) void cvtw_kernel(
    const float* __restrict__ s0, u16* __restrict__ d0,
    const float* __restrict__ s1, u16* __restrict__ d1,
    const float* __restrict__ s2, u16* __restrict__ d2,
    const float* __restrict__ s3, u16* __restrict__ d3)
{
  const float* s; u16* d;
  switch (blockIdx.y) {
    case 0:  s = s0; d = d0; break;
    case 1:  s = s1; d = d1; break;
    case 2:  s = s2; d = d2; break;
    default: s = s3; d = d3; break;
  }
  const size_t i = (size_t)blockIdx.x * 256 + threadIdx.x;
  const float4* f = (const float4*)(s + i * 8);
  const float4 lo = f[0], hi = f[1];
  *(bf16x8*)(d + i * 8) = cvt8(lo, hi);
}

// ---------------------------------------------------------------------------
// Fused QKV projection: C_z = X_z @ W_z^T + b_z, z in {V,K,Q}.
// grid (N/128, M/128, 3) = 1536 blocks = 6 blocks/CU of work (vs 512/2 before)
// -- the latency-hiding fix for the 12% MfmaUtil / 20% occupancy signature.
//
// X: f32, converted in-loop via cvt_pk (cheap). W: bf16 pre-converted, staged
// via global_load_lds w=16 (linear dest + inverse-swizzled source, rule #21).
// A: reg-staged with write-side swizzle (legal for ds_write). Both frag reads
// land on pitch-32 XOR-swizzled rows -> conflict-free ds_read_b128.
//
// launch_bounds(256,3): 170-reg cap. Unified need ~140 (64 AGPR acc + 16 f32
// prefetch + frags + addrs) -- the (256,4)/128-cap spill of rounds 4-5 stays
// avoided while still allowing 3 resident blocks/CU.
// ---------------------------------------------------------------------------
__global__ __launch_bounds__(256, 3) void qkv_fused_kernel(
    const float* __restrict__ Vx, const float* __restrict__ Kx,
    const float* __restrict__ Qx, const u16* __restrict__ Wb,
    const float* __restrict__ Bv, const float* __restrict__ Bk,
    const float* __restrict__ Bq,
    u16* __restrict__ cv, u16* __restrict__ ck, u16* __restrict__ cq,
    int N, int K)
{
  __shared__ __attribute__((aligned(16))) u16 Al[128 * 32];
  __shared__ __attribute__((aligned(16))) u16 Bl[128 * 32];

  const float* X; const u16* W; const float* Bias; u16* C;
  switch (blockIdx.z) {
    case 0:  X = Vx; W = Wb;                   Bias = Bv; C = cv; break;
    case 1:  X = Kx; W = Wb + EMB * EMB;       Bias = Bk; C = ck; break;
    default: X = Qx; W = Wb + 2 * EMB * EMB;   Bias = Bq; C = cq; break;
  }

  const int tid  = threadIdx.x;
  const int lane = tid & 63;
  const int w    = tid >> 6;
  const int wm = w >> 1, wn = w & 1;
  const int r16 = lane & 15, quad = lane >> 4;
  const int bm = blockIdx.y * 128, bn = blockIdx.x * 128;

  // --- A staging (reg -> swizzled ds_write): seg s = logical (row s>>2, slot s&3)
  const int s0 = tid, s1 = tid + 256;
  const int r0 = s0 >> 2, c0 = s0 & 3;
  const int r1 = s1 >> 2, c1 = s1 & 3;
  const int lA0 = r0 * 32 + ((c0 ^ (r0 & 3)) * 8);   // phys slot = c ^ (row&3)
  const int lA1 = r1 * 32 + ((c1 ^ (r1 & 3)) * 8);
  const size_t xo0 = (size_t)(bm + r0) * K + c0 * 8;
  const size_t xo1 = (size_t)(bm + r1) * K + c1 * 8;

  // --- B staging (gl16, linear dest): phys seg s holds logical slot (s&3)^(row&3)
  const int bs0 = w * 64 + lane, bs1 = bs0 + 256;
  const int br0 = bs0 >> 2, bc0 = ((bs0 & 3) ^ (br0 & 3)) * 8;
  const int br1 = bs1 >> 2, bc1 = ((bs1 & 3) ^ (br1 & 3)) * 8;
  const u16* srcB0 = W + (size_t)(bn + br0) * K + bc0;
  const u16* srcB1 = W + (size_t)(bn + br1) * K + bc1;
  u16* dB0 = Bl + (w * 64) * 8;        // wave-uniform base (+ lane*16B in HW)
  u16* dB1 = dB0 + 256 * 8;

  // --- frag read offsets: row*32 + (quad ^ (row&3))*8; row&3 == r16&3
  const int swz = (quad ^ (r16 & 3)) * 8;
  int offA[4], offB[4];
#pragma unroll
  for (int t = 0; t < 4; t++) {
    offA[t] = (wm * 64 + t * 16 + r16) * 32 + swz;
    offB[t] = (wn * 64 + t * 16 + r16) * 32 + swz;
  }

  f32x4 acc[4][4];
#pragma unroll
  for (int i = 0; i < 4; i++)
#pragma unroll
    for (int j = 0; j < 4; j++)
      acc[i][j] = f32x4{0.f, 0.f, 0.f, 0.f};

  // prefetch X k=0 (f32, converted at ds_write time)
  float4 xa0 = *(const float4*)(X + xo0), xa1 = *(const float4*)(X + xo0 + 4);
  float4 xb0 = *(const float4*)(X + xo1), xb1 = *(const float4*)(X + xo1 + 4);

  for (int k0 = 0; k0 < K; k0 += 32) {
    *(bf16x8*)&Al[lA0] = cvt8(xa0, xa1);
    *(bf16x8*)&Al[lA1] = cvt8(xb0, xb1);
    gl16(srcB0 + k0, dB0);
    gl16(srcB1 + k0, dB1);
    __syncthreads();               // drains lgkm (ds_write) + vmcnt (gl16)

    const int kn = (k0 + 32 < K) ? (k0 + 32) : 0;   // wrap: always-valid addrs
    xa0 = *(const float4*)(X + xo0 + kn); xa1 = *(const float4*)(X + xo0 + kn + 4);
    xb0 = *(const float4*)(X + xo1 + kn); xb1 = *(const float4*)(X + xo1 + kn + 4);

    bf16x8 a[4], b[4];
#pragma unroll
    for (int t = 0; t < 4; t++) a[t] = *(const bf16x8*)&Al[offA[t]];
#pragma unroll
    for (int t = 0; t < 4; t++) b[t] = *(const bf16x8*)&Bl[offB[t]];

#pragma unroll
    for (int tm = 0; tm < 4; tm++)
#pragma unroll
      for (int tn = 0; tn < 4; tn++)
        acc[tm][tn] = __builtin_amdgcn_mfma_f32_16x16x32_bf16(a[tm], b[tn], acc[tm][tn], 0, 0, 0);
    __syncthreads();
  }

  // C/D layout: col = lane&15, row = quad*4 + reg (verified m89/m91)
#pragma unroll
  for (int tn = 0; tn < 4; tn++) {
    const int col = bn + wn * 64 + tn * 16 + r16;
    const float bias = Bias[col];
#pragma unroll
    for (int tm = 0; tm < 4; tm++) {
      const int row0 = bm + wm * 64 + tm * 16 + quad * 4;
#pragma unroll
      for (int r = 0; r < 4; r++)
        C[(size_t)(row0 + r) * N + col] = f2bf(acc[tm][tn][r] + bias);
    }
  }
}

// ---------------------------------------------------------------------------
// Out projection: X bf16, W bf16, C f32. m97-style gl16 staging both sides,
// pitch-32 swizzled LDS (same addressing as the fused kernel's B side).
// ---------------------------------------------------------------------------
__global__ __launch_bounds__(256, 3) void out_gemm_kernel(
    const u16* __restrict__ X, const u16* __restrict__ W,
    const float* __restrict__ Bias, float* __restrict__ C, int N, int K)
{
  __shared__ __attribute__((aligned(16))) u16 Al[128 * 32];
  __shared__ __attribute__((aligned(16))) u16 Bl[128 * 32];

  const int tid  = threadIdx.x;
  const int lane = tid & 63;
  const int w    = tid >> 6;
  const int wm = w >> 1, wn = w & 1;
  const int r16 = lane & 15, quad = lane >> 4;
  const int bm = blockIdx.y * 128, bn = blockIdx.x * 128;

  const int s0 = w * 64 + lane, s1 = s0 + 256;
  const int r0 = s0 >> 2, c0 = ((s0 & 3) ^ (r0 & 3)) * 8;
  const int r1 = s1 >> 2, c1 = ((s1 & 3) ^ (r1 & 3)) * 8;

  const u16* srcA0 = X + (size_t)(bm + r0) * K + c0;
  const u16* srcA1 = X + (size_t)(bm + r1) * K + c1;
  const u16* srcB0 = W + (size_t)(bn + r0) * K + c0;
  const u16* srcB1 = W + (size_t)(bn + r1) * K + c1;

  u16* dA0 = Al + (w * 64) * 8;
  u16* dA1 = dA0 + 256 * 8;
  u16* dB0 = Bl + (w * 64) * 8;
  u16* dB1 = dB0 + 256 * 8;

  const int swz = (quad ^ (r16 & 3)) * 8;
  int offA[4], offB[4];
#pragma unroll
  for (int t = 0; t < 4; t++) {
    offA[t] = (wm * 64 + t * 16 + r16) * 32 + swz;
    offB[t] = (wn * 64 + t * 16 + r16) * 32 + swz;
  }

  f32x4 acc[4][4];
#pragma unroll
  for (int i = 0; i < 4; i++)
#pragma unroll
    for (int j = 0; j < 4; j++)
      acc[i][j] = f32x4{0.f, 0.f, 0.f, 0.f};

  for (int k0 = 0; k0 < K; k0 += 32) {
    gl16(srcA0 + k0, dA0);
    gl16(srcA1 + k0, dA1);
    gl16(srcB0 + k0, dB0);
    gl16(srcB1 + k0, dB1);
    __syncthreads();

    bf16x8 a[4], b[4];
#pragma unroll
    for (int t = 0; t < 4; t++) a[t] = *(const bf16x8*)&Al[offA[t]];
#pragma unroll
    for (int t = 0; t < 4; t++) b[t] = *(const bf16x8*)&Bl[offB[t]];

#pragma unroll
    for (int tm = 0; tm < 4; tm++)
#pragma unroll
      for (int tn = 0; tn < 4; tn++)
        acc[tm][tn] = __builtin_amdgcn_mfma_f32_16x16x32_bf16(a[tm], b[tn], acc[tm][tn], 0, 0, 0);
    __syncthreads();
  }

#pragma unroll
  for (int tn = 0; tn < 4; tn++) {
    const int col = bn + wn * 64 + tn * 16 + r16;
    const float bias = Bias[col];
#pragma unroll
    for (int tm = 0; tm < 4; tm++) {
      const int row0 = bm + wm * 64 + tm * 16 + quad * 4;
#pragma unroll
      for (int r = 0; r < 4; r++)
        C[(size_t)(row0 + r) * N + col] = acc[tm][tn][r] + bias;
    }
  }
}

// ---------------------------------------------------------------------------
// Per-token head-mixing attention (unchanged; 4 blocks/CU).
// ---------------------------------------------------------------------------
__global__ __launch_bounds__(256, 4) void attn_heads_kernel(
    const u16* Q, const u16* Km, const u16* V, u16* O)
{
  __shared__ __attribute__((aligned(16))) u16 P[4][16 * LROW];
  __shared__ __attribute__((aligned(16))) u16 VT[4][64 * LROW];

  const int tid = threadIdx.x, lane = tid & 63, w = tid >> 6;
  const int r16 = lane & 15, quad = lane >> 4;
  const size_t base = ((size_t)blockIdx.x * 4 + w) * EMB;

  const bf16x8 aq0 = *(const bf16x8*)&Q[base + r16 * 64 + quad * 8];
  const bf16x8 aq1 = *(const bf16x8*)&Q[base + r16 * 64 + 32 + quad * 8];
  const bf16x8 bk0 = *(const bf16x8*)&Km[base + r16 * 64 + quad * 8];
  const bf16x8 bk1 = *(const bf16x8*)&Km[base + r16 * 64 + 32 + quad * 8];

  const u16x8 v0 = *(const u16x8*)&V[base + lane * 16];
  const u16x8 v1 = *(const u16x8*)&V[base + lane * 16 + 8];
  const u16x8 z8 = {0, 0, 0, 0, 0, 0, 0, 0};
  *(u16x8*)&VT[w][lane * LROW + 16] = z8;
  *(u16x8*)&VT[w][lane * LROW + 24] = z8;
  const int g = lane >> 2, dbase = (lane & 3) * 16;
#pragma unroll
  for (int i = 0; i < 8; i++) {
    VT[w][(dbase + i) * LROW + g]     = v0[i];
    VT[w][(dbase + 8 + i) * LROW + g] = v1[i];
  }

  f32x4 s = f32x4{0.f, 0.f, 0.f, 0.f};
  s = __builtin_amdgcn_mfma_f32_16x16x32_bf16(aq0, bk0, s, 0, 0, 0);
  s = __builtin_amdgcn_mfma_f32_16x16x32_bf16(aq1, bk1, s, 0, 0, 0);

  float p[4];
#pragma unroll
  for (int r = 0; r < 4; r++) {
    float v = s[r] * 0.125f;
    float m = v;
#pragma unroll
    for (int d = 8; d; d >>= 1) m = fmaxf(m, __shfl_xor(m, d, 16));
    float e = __expf(v - m);
    float sum = e;
#pragma unroll
    for (int d = 8; d; d >>= 1) sum += __shfl_xor(sum, d, 16);
    p[r] = e / sum;
  }

#pragma unroll
  for (int r = 0; r < 4; r++) {
    P[w][(quad * 4 + r) * LROW + r16]      = f2bf(p[r]);
    P[w][(quad * 4 + r) * LROW + 16 + r16] = 0;
  }
  __syncthreads();

  const bf16x8 pa = *(const bf16x8*)&P[w][r16 * LROW + quad * 8];

#pragma unroll
  for (int c = 0; c < 4; c++) {
    const bf16x8 bvv = *(const bf16x8*)&VT[w][(c * 16 + r16) * LROW + quad * 8];
    f32x4 o = f32x4{0.f, 0.f, 0.f, 0.f};
    o = __builtin_amdgcn_mfma_f32_16x16x32_bf16(pa, bvv, o, 0, 0, 0);
#pragma unroll
    for (int r = 0; r < 4; r++)
      O[base + (size_t)(quad * 4 + r) * 64 + c * 16 + r16] = f2bf(o[r]);
  }
}

// ---------------------------------------------------------------------------
// Orchestration. ws: q | k (proven 33.55 MB) + optional 2 MB tail for Wo bf16
// (guarded by ws_size check; fallback = post-attn cvt into dead k region).
// d_out: lower half = v (bf16), upper half = Wqkv bf16 (6 MB, read-only
// during the fused GEMM -- distinct half from the v writes).
// Launches: 5 (was 9) -- cvtw, qkv_fused, attn, [cvt Wo], out_gemm.
// ---------------------------------------------------------------------------
extern "C" void kernel_launch(void* const* d_in, const int* in_sizes, int n_in,
                              void* d_out, int out_size, void* d_ws, size_t ws_size,
                              hipStream_t stream)
{
  const float* values = (const float*)d_in[0];
  const float* keys   = (const float*)d_in[1];
  const float* query  = (const float*)d_in[2];
  const float* Wv = (const float*)d_in[3];
  const float* bv = (const float*)d_in[4];
  const float* Wk = (const float*)d_in[5];
  const float* bk = (const float*)d_in[6];
  const float* Wq = (const float*)d_in[7];
  const float* bq = (const float*)d_in[8];
  const float* Wo = (const float*)d_in[9];
  const float* bo = (const float*)d_in[10];

  const int M = in_sizes[0] / EMB;   // 8192 tokens
  const int N = EMB, K = EMB;

  u16* q    = (u16*)d_ws;                 // M*EMB bf16
  u16* kbuf = q + (size_t)M * EMB;        // M*EMB bf16
  u16* v    = (u16*)d_out;                // d_out lower half
  u16* wb   = v + (size_t)M * EMB;        // d_out upper half: Wv|Wk|Wq bf16
  u16* ao   = q;                          // attention out aliases q

  const size_t base_ws = (size_t)2 * M * EMB * sizeof(u16);
  const bool wo_in_ws = ws_size >= base_ws + (size_t)EMB * EMB * sizeof(u16);
  u16* wob = wo_in_ws ? kbuf + (size_t)M * EMB : kbuf;

  dim3 blk(256, 1, 1);
  dim3 cwg(EMB * EMB / 8 / 256, wo_in_ws ? 4 : 3, 1);

  // weights -> bf16 (Wo fused in when ws tail is available)
  hipLaunchKernelGGL(cvtw_kernel, cwg, blk, 0, stream,
                     Wv, wb, Wk, wb + EMB * EMB, Wq, wb + 2 * EMB * EMB, Wo, wob);
  // fused QKV projections (1536 blocks)
  hipLaunchKernelGGL(qkv_fused_kernel, dim3(N / 128, M / 128, 3), blk, 0, stream,
                     values, keys, query, wb, bv, bk, bq, v, kbuf, q, N, K);
  // attention
  hipLaunchKernelGGL(attn_heads_kernel, dim3(M / 4, 1, 1), blk, 0, stream,
                     q, kbuf, v, ao);
  // Wo fallback home: dead k region
  if (!wo_in_ws)
    hipLaunchKernelGGL(cvtw_kernel, dim3(EMB * EMB / 8 / 256, 1, 1), blk, 0, stream,
                       Wo, wob, (const float*)nullptr, (u16*)nullptr,
                       (const float*)nullptr, (u16*)nullptr,
                       (const float*)nullptr, (u16*)nullptr);
  // output projection (writes all of d_out f32; v and wb dead)
  hipLaunchKernelGGL(out_gemm_kernel, dim3(N / 128, M / 128, 1), blk, 0, stream,
                     ao, wob, bo, (float*)d_out, N, K);
}

// Round 4
// 282.250 us; speedup vs baseline: 1.3219x; 1.0565x over previous
//
#include <hip/hip_runtime.h>
#include <stdint.h>

#define EMB 1024
#define LROW 40   // attn-kernel LDS pitch (u16)

typedef unsigned short u16;
typedef __attribute__((ext_vector_type(8))) unsigned short u16x8;
typedef __attribute__((ext_vector_type(8))) __bf16 bf16x8;
typedef __attribute__((ext_vector_type(4))) float f32x4;

__device__ __forceinline__ u16 f2bf(float f) {
  union { float f; uint32_t u; } x; x.f = f;
  uint32_t u = x.u;
  u += 0x7fff + ((u >> 16) & 1u);   // round-to-nearest-even
  return (u16)(u >> 16);
}

// 8x f32 -> bf16x8 via native casts (v_cvt_pk_bf16_f32).
__device__ __forceinline__ bf16x8 cvt8(float4 a, float4 b) {
  bf16x8 r;
  r[0] = (__bf16)a.x; r[1] = (__bf16)a.y; r[2] = (__bf16)a.z; r[3] = (__bf16)a.w;
  r[4] = (__bf16)b.x; r[5] = (__bf16)b.y; r[6] = (__bf16)b.z; r[7] = (__bf16)b.w;
  return r;
}

// Async global->LDS, 16B per lane. LDS dest is wave-uniform base + lane*16.
__device__ __forceinline__ void gl16(const u16* g, u16* l) {
  __builtin_amdgcn_global_load_lds(
      (const __attribute__((address_space(1))) void*)g,
      (__attribute__((address_space(3))) void*)l, 16, 0, 0);
}

// XCD-chunked block swizzle (m157; requires nwg % 8 == 0 -- 1536/512 both ok).
// Consecutive LOGICAL blocks land on the SAME XCD -> L2 panel reuse.
__device__ __forceinline__ int xcd_logical(int orig, int nwg) {
  return (orig & 7) * (nwg >> 3) + (orig >> 3);
}

// ---------------------------------------------------------------------------
// Weight cvt: y-indexed (src,dst) pairs, each exactly EMB*EMB elements.
// ---------------------------------------------------------------------------
__global__ __launch_bounds__(256) void cvtw_kernel(
    const float* __restrict__ s0, u16* __restrict__ d0,
    const float* __restrict__ s1, u16* __restrict__ d1,
    const float* __restrict__ s2, u16* __restrict__ d2,
    const float* __restrict__ s3, u16* __restrict__ d3)
{
  const float* s; u16* d;
  switch (blockIdx.y) {
    case 0:  s = s0; d = d0; break;
    case 1:  s = s1; d = d1; break;
    case 2:  s = s2; d = d2; break;
    default: s = s3; d = d3; break;
  }
  const size_t i = (size_t)blockIdx.x * 256 + threadIdx.x;
  const float4* f = (const float4*)(s + i * 8);
  const float4 lo = f[0], hi = f[1];
  *(bf16x8*)(d + i * 8) = cvt8(lo, hi);
}

// ---------------------------------------------------------------------------
// Fused QKV projection: C_z = X_z @ W_z^T + b_z, z in {V,K,Q}. 1536 blocks,
// 1D grid + XCD-chunked swizzle: each XCD owns contiguous M-panels x all 8
// N-tiles -> X panel reused 8x in its private L2, W (2MB) L2-resident.
//
// LDS swizzle (both GEMMs): phys slot = logical slot ^ ((row>>1)&3) on
// 64B-pitch rows. Every consecutive-8-lane phase of ds_read_b128 /
// ds_write_b128 is then a perfect permutation of the 8 bank groups
// (enumerated; the previous (row&3) form was 2-way per phase = the 6.29M
// conflict count of round 2). gl16 keeps a LINEAR dest; the same involution
// is applied to its SOURCE address (rule #21).
// ---------------------------------------------------------------------------
__global__ __launch_bounds__(256, 3) void qkv_fused_kernel(
    const float* __restrict__ Vx, const float* __restrict__ Kx,
    const float* __restrict__ Qx, const u16* __restrict__ Wb,
    const float* __restrict__ Bv, const float* __restrict__ Bk,
    const float* __restrict__ Bq,
    u16* __restrict__ cv, u16* __restrict__ ck, u16* __restrict__ cq,
    int N, int K, int M)
{
  __shared__ __attribute__((aligned(16))) u16 Al[128 * 32];
  __shared__ __attribute__((aligned(16))) u16 Bl[128 * 32];

  const int nwg = (N >> 7) * (M >> 7) * 3;
  const int logical = xcd_logical(blockIdx.x, nwg);
  const int per_z = (N >> 7) * (M >> 7);
  const int z = logical / per_z;
  const int rem = logical - z * per_z;
  const int nbx = N >> 7;
  const int by = rem / nbx, bx = rem - by * nbx;   // bx fastest within chunk

  const float* X; const u16* W; const float* Bias; u16* C;
  switch (z) {
    case 0:  X = Vx; W = Wb;                   Bias = Bv; C = cv; break;
    case 1:  X = Kx; W = Wb + EMB * EMB;       Bias = Bk; C = ck; break;
    default: X = Qx; W = Wb + 2 * EMB * EMB;   Bias = Bq; C = cq; break;
  }

  const int tid  = threadIdx.x;
  const int lane = tid & 63;
  const int w    = tid >> 6;
  const int wm = w >> 1, wn = w & 1;
  const int r16 = lane & 15, quad = lane >> 4;
  const int bm = by * 128, bn = bx * 128;

  // --- A staging (reg -> swizzled ds_write): thread owns logical (r,c)
  const int s0 = tid, s1 = tid + 256;
  const int r0 = s0 >> 2, c0 = s0 & 3;
  const int r1 = s1 >> 2, c1 = s1 & 3;
  const int lA0 = r0 * 32 + ((c0 ^ ((r0 >> 1) & 3)) * 8);
  const int lA1 = r1 * 32 + ((c1 ^ ((r1 >> 1) & 3)) * 8);
  const size_t xo0 = (size_t)(bm + r0) * K + c0 * 8;
  const size_t xo1 = (size_t)(bm + r1) * K + c1 * 8;

  // --- B staging (gl16, linear dest): phys seg s holds logical slot
  //     (s&3) ^ ((row>>1)&3)  -> pre-swizzled global source column.
  const int bs0 = w * 64 + lane, bs1 = bs0 + 256;
  const int br0 = bs0 >> 2, bc0 = ((bs0 & 3) ^ ((br0 >> 1) & 3)) * 8;
  const int br1 = bs1 >> 2, bc1 = ((bs1 & 3) ^ ((br1 >> 1) & 3)) * 8;
  const u16* srcB0 = W + (size_t)(bn + br0) * K + bc0;
  const u16* srcB1 = W + (size_t)(bn + br1) * K + bc1;
  u16* dB0 = Bl + (w * 64) * 8;
  u16* dB1 = dB0 + 256 * 8;

  // --- frag reads: slot = quad ^ ((r16>>1)&3)  (row base mult of 16)
  const int swz = (quad ^ ((r16 >> 1) & 3)) * 8;
  int offA[4], offB[4];
#pragma unroll
  for (int t = 0; t < 4; t++) {
    offA[t] = (wm * 64 + t * 16 + r16) * 32 + swz;
    offB[t] = (wn * 64 + t * 16 + r16) * 32 + swz;
  }

  f32x4 acc[4][4];
#pragma unroll
  for (int i = 0; i < 4; i++)
#pragma unroll
    for (int j = 0; j < 4; j++)
      acc[i][j] = f32x4{0.f, 0.f, 0.f, 0.f};

  float4 xa0 = *(const float4*)(X + xo0), xa1 = *(const float4*)(X + xo0 + 4);
  float4 xb0 = *(const float4*)(X + xo1), xb1 = *(const float4*)(X + xo1 + 4);

  for (int k0 = 0; k0 < K; k0 += 32) {
    *(bf16x8*)&Al[lA0] = cvt8(xa0, xa1);
    *(bf16x8*)&Al[lA1] = cvt8(xb0, xb1);
    gl16(srcB0 + k0, dB0);
    gl16(srcB1 + k0, dB1);
    __syncthreads();

    const int kn = (k0 + 32 < K) ? (k0 + 32) : 0;
    xa0 = *(const float4*)(X + xo0 + kn); xa1 = *(const float4*)(X + xo0 + kn + 4);
    xb0 = *(const float4*)(X + xo1 + kn); xb1 = *(const float4*)(X + xo1 + kn + 4);

    bf16x8 a[4], b[4];
#pragma unroll
    for (int t = 0; t < 4; t++) a[t] = *(const bf16x8*)&Al[offA[t]];
#pragma unroll
    for (int t = 0; t < 4; t++) b[t] = *(const bf16x8*)&Bl[offB[t]];

#pragma unroll
    for (int tm = 0; tm < 4; tm++)
#pragma unroll
      for (int tn = 0; tn < 4; tn++)
        acc[tm][tn] = __builtin_amdgcn_mfma_f32_16x16x32_bf16(a[tm], b[tn], acc[tm][tn], 0, 0, 0);
    __syncthreads();
  }

  // C/D layout: col = lane&15, row = quad*4 + reg (verified m89/m91)
#pragma unroll
  for (int tn = 0; tn < 4; tn++) {
    const int col = bn + wn * 64 + tn * 16 + r16;
    const float bias = Bias[col];
#pragma unroll
    for (int tm = 0; tm < 4; tm++) {
      const int row0 = bm + wm * 64 + tm * 16 + quad * 4;
#pragma unroll
      for (int r = 0; r < 4; r++)
        C[(size_t)(row0 + r) * N + col] = f2bf(acc[tm][tn][r] + bias);
    }
  }
}

// ---------------------------------------------------------------------------
// Out projection: X bf16, W bf16, C f32. gl16 both sides, same swizzle,
// same XCD chunking (512 blocks, 64/XCD = 8 M-panels x 8 N-tiles).
// ---------------------------------------------------------------------------
__global__ __launch_bounds__(256, 3) void out_gemm_kernel(
    const u16* __restrict__ X, const u16* __restrict__ W,
    const float* __restrict__ Bias, float* __restrict__ C, int N, int K, int M)
{
  __shared__ __attribute__((aligned(16))) u16 Al[128 * 32];
  __shared__ __attribute__((aligned(16))) u16 Bl[128 * 32];

  const int nwg = (N >> 7) * (M >> 7);
  const int logical = xcd_logical(blockIdx.x, nwg);
  const int nbx = N >> 7;
  const int by = logical / nbx, bx = logical - by * nbx;

  const int tid  = threadIdx.x;
  const int lane = tid & 63;
  const int w    = tid >> 6;
  const int wm = w >> 1, wn = w & 1;
  const int r16 = lane & 15, quad = lane >> 4;
  const int bm = by * 128, bn = bx * 128;

  const int s0 = w * 64 + lane, s1 = s0 + 256;
  const int r0 = s0 >> 2, c0 = ((s0 & 3) ^ ((r0 >> 1) & 3)) * 8;
  const int r1 = s1 >> 2, c1 = ((s1 & 3) ^ ((r1 >> 1) & 3)) * 8;

  const u16* srcA0 = X + (size_t)(bm + r0) * K + c0;
  const u16* srcA1 = X + (size_t)(bm + r1) * K + c1;
  const u16* srcB0 = W + (size_t)(bn + r0) * K + c0;
  const u16* srcB1 = W + (size_t)(bn + r1) * K + c1;

  u16* dA0 = Al + (w * 64) * 8;
  u16* dA1 = dA0 + 256 * 8;
  u16* dB0 = Bl + (w * 64) * 8;
  u16* dB1 = dB0 + 256 * 8;

  const int swz = (quad ^ ((r16 >> 1) & 3)) * 8;
  int offA[4], offB[4];
#pragma unroll
  for (int t = 0; t < 4; t++) {
    offA[t] = (wm * 64 + t * 16 + r16) * 32 + swz;
    offB[t] = (wn * 64 + t * 16 + r16) * 32 + swz;
  }

  f32x4 acc[4][4];
#pragma unroll
  for (int i = 0; i < 4; i++)
#pragma unroll
    for (int j = 0; j < 4; j++)
      acc[i][j] = f32x4{0.f, 0.f, 0.f, 0.f};

  for (int k0 = 0; k0 < K; k0 += 32) {
    gl16(srcA0 + k0, dA0);
    gl16(srcA1 + k0, dA1);
    gl16(srcB0 + k0, dB0);
    gl16(srcB1 + k0, dB1);
    __syncthreads();

    bf16x8 a[4], b[4];
#pragma unroll
    for (int t = 0; t < 4; t++) a[t] = *(const bf16x8*)&Al[offA[t]];
#pragma unroll
    for (int t = 0; t < 4; t++) b[t] = *(const bf16x8*)&Bl[offB[t]];

#pragma unroll
    for (int tm = 0; tm < 4; tm++)
#pragma unroll
      for (int tn = 0; tn < 4; tn++)
        acc[tm][tn] = __builtin_amdgcn_mfma_f32_16x16x32_bf16(a[tm], b[tn], acc[tm][tn], 0, 0, 0);
    __syncthreads();
  }

#pragma unroll
  for (int tn = 0; tn < 4; tn++) {
    const int col = bn + wn * 64 + tn * 16 + r16;
    const float bias = Bias[col];
#pragma unroll
    for (int tm = 0; tm < 4; tm++) {
      const int row0 = bm + wm * 64 + tm * 16 + quad * 4;
#pragma unroll
      for (int r = 0; r < 4; r++)
        C[(size_t)(row0 + r) * N + col] = acc[tm][tn][r] + bias;
    }
  }
}

// ---------------------------------------------------------------------------
// Per-token head-mixing attention (unchanged; no inter-block reuse -> no
// XCD swizzle, T1 null on streaming ops).
// ---------------------------------------------------------------------------
__global__ __launch_bounds__(256, 4) void attn_heads_kernel(
    const u16* Q, const u16* Km, const u16* V, u16* O)
{
  __shared__ __attribute__((aligned(16))) u16 P[4][16 * LROW];
  __shared__ __attribute__((aligned(16))) u16 VT[4][64 * LROW];

  const int tid = threadIdx.x, lane = tid & 63, w = tid >> 6;
  const int r16 = lane & 15, quad = lane >> 4;
  const size_t base = ((size_t)blockIdx.x * 4 + w) * EMB;

  const bf16x8 aq0 = *(const bf16x8*)&Q[base + r16 * 64 + quad * 8];
  const bf16x8 aq1 = *(const bf16x8*)&Q[base + r16 * 64 + 32 + quad * 8];
  const bf16x8 bk0 = *(const bf16x8*)&Km[base + r16 * 64 + quad * 8];
  const bf16x8 bk1 = *(const bf16x8*)&Km[base + r16 * 64 + 32 + quad * 8];

  const u16x8 v0 = *(const u16x8*)&V[base + lane * 16];
  const u16x8 v1 = *(const u16x8*)&V[base + lane * 16 + 8];
  const u16x8 z8 = {0, 0, 0, 0, 0, 0, 0, 0};
  *(u16x8*)&VT[w][lane * LROW + 16] = z8;
  *(u16x8*)&VT[w][lane * LROW + 24] = z8;
  const int g = lane >> 2, dbase = (lane & 3) * 16;
#pragma unroll
  for (int i = 0; i < 8; i++) {
    VT[w][(dbase + i) * LROW + g]     = v0[i];
    VT[w][(dbase + 8 + i) * LROW + g] = v1[i];
  }

  f32x4 s = f32x4{0.f, 0.f, 0.f, 0.f};
  s = __builtin_amdgcn_mfma_f32_16x16x32_bf16(aq0, bk0, s, 0, 0, 0);
  s = __builtin_amdgcn_mfma_f32_16x16x32_bf16(aq1, bk1, s, 0, 0, 0);

  float p[4];
#pragma unroll
  for (int r = 0; r < 4; r++) {
    float v = s[r] * 0.125f;
    float m = v;
#pragma unroll
    for (int d = 8; d; d >>= 1) m = fmaxf(m, __shfl_xor(m, d, 16));
    float e = __expf(v - m);
    float sum = e;
#pragma unroll
    for (int d = 8; d; d >>= 1) sum += __shfl_xor(sum, d, 16);
    p[r] = e / sum;
  }

#pragma unroll
  for (int r = 0; r < 4; r++) {
    P[w][(quad * 4 + r) * LROW + r16]      = f2bf(p[r]);
    P[w][(quad * 4 + r) * LROW + 16 + r16] = 0;
  }
  __syncthreads();

  const bf16x8 pa = *(const bf16x8*)&P[w][r16 * LROW + quad * 8];

#pragma unroll
  for (int c = 0; c < 4; c++) {
    const bf16x8 bvv = *(const bf16x8*)&VT[w][(c * 16 + r16) * LROW + quad * 8];
    f32x4 o = f32x4{0.f, 0.f, 0.f, 0.f};
    o = __builtin_amdgcn_mfma_f32_16x16x32_bf16(pa, bvv, o, 0, 0, 0);
#pragma unroll
    for (int r = 0; r < 4; r++)
      O[base + (size_t)(quad * 4 + r) * 64 + c * 16 + r16] = f2bf(o[r]);
  }
}

// ---------------------------------------------------------------------------
// Orchestration (unchanged layout). ws: q | k + optional 2MB Wo tail.
// d_out: lower half = v (bf16), upper half = Wqkv bf16.
// ---------------------------------------------------------------------------
extern "C" void kernel_launch(void* const* d_in, const int* in_sizes, int n_in,
                              void* d_out, int out_size, void* d_ws, size_t ws_size,
                              hipStream_t stream)
{
  const float* values = (const float*)d_in[0];
  const float* keys   = (const float*)d_in[1];
  const float* query  = (const float*)d_in[2];
  const float* Wv = (const float*)d_in[3];
  const float* bv = (const float*)d_in[4];
  const float* Wk = (const float*)d_in[5];
  const float* bk = (const float*)d_in[6];
  const float* Wq = (const float*)d_in[7];
  const float* bq = (const float*)d_in[8];
  const float* Wo = (const float*)d_in[9];
  const float* bo = (const float*)d_in[10];

  const int M = in_sizes[0] / EMB;   // 8192 tokens
  const int N = EMB, K = EMB;

  u16* q    = (u16*)d_ws;
  u16* kbuf = q + (size_t)M * EMB;
  u16* v    = (u16*)d_out;
  u16* wb   = v + (size_t)M * EMB;
  u16* ao   = q;

  const size_t base_ws = (size_t)2 * M * EMB * sizeof(u16);
  const bool wo_in_ws = ws_size >= base_ws + (size_t)EMB * EMB * sizeof(u16);
  u16* wob = wo_in_ws ? kbuf + (size_t)M * EMB : kbuf;

  dim3 blk(256, 1, 1);
  dim3 cwg(EMB * EMB / 8 / 256, wo_in_ws ? 4 : 3, 1);

  hipLaunchKernelGGL(cvtw_kernel, cwg, blk, 0, stream,
                     Wv, wb, Wk, wb + EMB * EMB, Wq, wb + 2 * EMB * EMB, Wo, wob);
  hipLaunchKernelGGL(qkv_fused_kernel, dim3((N / 128) * (M / 128) * 3, 1, 1), blk, 0, stream,
                     values, keys, query, wb, bv, bk, bq, v, kbuf, q, N, K, M);
  hipLaunchKernelGGL(attn_heads_kernel, dim3(M / 4, 1, 1), blk, 0, stream,
                     q, kbuf, v, ao);
  if (!wo_in_ws)
    hipLaunchKernelGGL(cvtw_kernel, dim3(EMB * EMB / 8 / 256, 1, 1), blk, 0, stream,
                       Wo, wob, (const float*)nullptr, (u16*)nullptr,
                       (const float*)nullptr, (u16*)nullptr,
                       (const float*)nullptr, (u16*)nullptr);
  hipLaunchKernelGGL(out_gemm_kernel, dim3((N / 128) * (M / 128), 1, 1), blk, 0, stream,
                     ao, wob, bo, (float*)d_out, N, K, M);
}